// Round 9
// baseline (284.459 us; speedup 1.0000x reference)
//
#include <hip/hip_runtime.h>
#include <math.h>

// Problem: scores = q[2048x768] @ p[16384x768]^T (fp32 in), per-query
// rank-of-target + log-softmax CE + Gaussian rank weight -> mean (scalar).
// R9: barrier-free fp8 GEMM + REGISTER-ROTATED PIPELINE. No LDS/barriers
// (R8); K-loop split into 32-k half-phases, 2-deep register double-buffer:
// load phase p+1 (8 dwordx2, canonical fp8 fragment k=lq*8+j) while the
// MFMA pipe chews phase p (16 MFMAs). R8 lesson: without this, every phase
// pays full VMEM latency serially (MfmaUtil 18%). Register budget:
// 64 acc(AGPR) + 32 frag + ~10 addr = ~106 <= 128 @ (512,4), 2 blocks/CU.

#define BQ 2048
#define DD 768
#define NPASS 8
#define PP 16384
#define BM 256
#define BN 128
#define NPH 24             // 768/32 half-phases
#define NBLK 128           // PP/BN
#define MBLK 8             // BQ/BM
#define NCHUNKS 256        // NBLK * 2 wn-groups

#define ALPHA_C 2.6f
#define INV_2SIG2 (1.0f/6.48f)   // 1/(2*1.8^2)

typedef __attribute__((ext_vector_type(4))) float floatx4;  // MFMA C/D

// ---------------------------------------------------------------------------
// Kernel 1 (fused): cast q,p -> fp8 e4m3  +  s_t exact-fp32 dots  +  out=0.
// ---------------------------------------------------------------------------
#define NQ8   196608     // 2048*768/8
#define NTOT8 1769472    // (2048+16384)*768/8
#define NCB   6912       // NTOT8/256
__global__ __launch_bounds__(256) void prep_kernel(const float* __restrict__ qf,
                                                   const float* __restrict__ pf,
                                                   uint2* __restrict__ qb,
                                                   uint2* __restrict__ pb,
                                                   float* __restrict__ st,
                                                   float* __restrict__ out) {
  const int b = blockIdx.x;
  if (b == 0 && threadIdx.x == 0) *out = 0.f;
  if (b < NCB) {
    const int i = b * 256 + threadIdx.x;        // float8 index
    const float4* src; uint2* dst;
    if (i < NQ8) { src = (const float4*)qf + 2 * (size_t)i; dst = qb + i; }
    else { const size_t j = (size_t)i - NQ8; src = (const float4*)pf + 2 * j; dst = pb + j; }
    const float4 a = src[0], c = src[1];
    unsigned lo = __builtin_amdgcn_cvt_pk_fp8_f32(a.x, a.y, 0, 0);
    lo = __builtin_amdgcn_cvt_pk_fp8_f32(a.z, a.w, lo, 1);
    unsigned hi = __builtin_amdgcn_cvt_pk_fp8_f32(c.x, c.y, 0, 0);
    hi = __builtin_amdgcn_cvt_pk_fp8_f32(c.z, c.w, hi, 1);
    uint2 w; w.x = lo; w.y = hi;
    *dst = w;
  } else {
    const int wv = threadIdx.x >> 6, lane = threadIdx.x & 63;
    const int qi = (b - NCB) * 4 + wv;
    const float4* q4 = (const float4*)(qf + (size_t)qi * DD);
    const float4* p4 = (const float4*)(pf + (size_t)qi * NPASS * DD);
    float acc = 0.f;
#pragma unroll
    for (int u = 0; u < 3; ++u) {
      float4 a = q4[lane + 64 * u];
      float4 c = p4[lane + 64 * u];
      acc = fmaf(a.x, c.x, acc);
      acc = fmaf(a.y, c.y, acc);
      acc = fmaf(a.z, c.z, acc);
      acc = fmaf(a.w, c.w, acc);
    }
#pragma unroll
    for (int off = 32; off >= 1; off >>= 1) acc += __shfl_xor(acc, off);
    if (lane == 0) st[qi] = acc;
  }
}

// ---------------------------------------------------------------------------
// Kernel 2: barrier-free fp8 MFMA GEMM 256x128, register-pipelined, no LDS.
// 8 waves as 4 wm x 2 wn; each wave owns 64x64 (4x4 frags of 16x16).
// Half-phase ph (32 k): 8 dwordx2 loads — lane(lm=lane&15,lq=lane>>4) reads
// row (tile+frag*16+lm), bytes ph*32 + lq*8 (canonical fp8 16x16x32 A/B
// fragment) — then 16 MFMAs. 2-deep rotation hides VMEM latency under the
// previous phase's MFMA pipe time. C/D: col=lane&15, row=(lane>>4)*4+reg.
// Grid: mb=bid&7 (one m-slice per XCD, L2-resident), nb=bid>>3.
// ---------------------------------------------------------------------------
__global__ __launch_bounds__(512, 4) void gemm_kernel(const unsigned char* __restrict__ qb,
                                                      const unsigned char* __restrict__ pb,
                                                      const float* __restrict__ st,
                                                      float* __restrict__ pm,
                                                      float* __restrict__ pl,
                                                      float* __restrict__ pc) {
  const int t = threadIdx.x;
  const int lane = t & 63;
  const int wv = t >> 6;            // 0..7
  const int wm = wv >> 1, wn = wv & 1;
  const int bid = blockIdx.x;
  const int mb = bid & 7;           // XCD round-robin: one m-slice per XCD
  const int nb = bid >> 3;
  const int qbase = mb * BM;
  const int n0 = nb * BN;
  const int lm = lane & 15;
  const int lq = lane >> 4;

  floatx4 acc[4][4];
#pragma unroll
  for (int i = 0; i < 4; ++i)
#pragma unroll
    for (int j = 0; j < 4; ++j) acc[i][j] = (floatx4){0.f, 0.f, 0.f, 0.f};

  // per-lane fragment base pointers (row*DD + lq*8), frag f at +f*16*DD
  const unsigned char* ap = qb + (size_t)(qbase + wm * 64 + lm) * DD + lq * 8;
  const unsigned char* bp = pb + (size_t)(n0 + wn * 64 + lm) * DD + lq * 8;

  long ar[2][4], br[2][4];   // 2-deep rotation buffers (32 VGPRs)

#define LOADH(PH, BUF)                                                \
  {                                                                   \
    const int _ko = (PH) * 32;                                        \
    _Pragma("unroll")                                                 \
    for (int f = 0; f < 4; ++f) {                                     \
      ar[BUF][f] = *(const long*)(ap + f * (16 * DD) + _ko);          \
      br[BUF][f] = *(const long*)(bp + f * (16 * DD) + _ko);          \
    }                                                                 \
  }
#define MFMAH(BUF)                                                    \
  {                                                                   \
    _Pragma("unroll")                                                 \
    for (int i = 0; i < 4; ++i)                                       \
      _Pragma("unroll")                                               \
      for (int j = 0; j < 4; ++j)                                     \
        acc[i][j] = __builtin_amdgcn_mfma_f32_16x16x32_fp8_fp8(       \
            ar[BUF][i], br[BUF][j], acc[i][j], 0, 0, 0);              \
  }

  LOADH(0, 0)
#pragma unroll
  for (int ph = 0; ph < NPH; ph += 2) {
    if (ph + 1 < NPH) LOADH(ph + 1, 1)   // prefetch under MFMAs below
    MFMAH(0)
    if (ph + 2 < NPH) LOADH(ph + 2, 0)
    MFMAH(1)
  }
#undef LOADH
#undef MFMAH

  // ---- fused epilogue: per-row (query) max / sumexp / count over 64 cols ----
#pragma unroll
  for (int i = 0; i < 4; ++i) {
#pragma unroll
    for (int r = 0; r < 4; ++r) {
      const int rl = wm * 64 + i * 16 + lq * 4 + r;   // local query row
      const int qg = qbase + rl;
      float mx = fmaxf(fmaxf(acc[i][0][r], acc[i][1][r]),
                       fmaxf(acc[i][2][r], acc[i][3][r]));
#pragma unroll
      for (int off = 1; off <= 8; off <<= 1) mx = fmaxf(mx, __shfl_xor(mx, off));
      const float stv = st[qg];
      const int tcol = qg * NPASS;
      float sum = 0.f, c = 0.f;
#pragma unroll
      for (int j = 0; j < 4; ++j) {
        const float s = acc[i][j][r];
        sum += __expf(s - mx);
        const int cg = n0 + wn * 64 + j * 16 + lm;
        if (s > stv && cg != tcol) c += 1.f;
      }
#pragma unroll
      for (int off = 1; off <= 8; off <<= 1) {
        sum += __shfl_xor(sum, off);
        c += __shfl_xor(c, off);
      }
      if (lm == 0) {
        const int chunk = nb * 2 + wn;
        const size_t idx = (size_t)qg * NCHUNKS + chunk;
        pm[idx] = mx; pl[idx] = sum; pc[idx] = c;
      }
    }
  }
}

// ---------------------------------------------------------------------------
// Kernel 3: merge 256 chunks/query, weighted CE, mean -> atomicAdd. 1 wave/query.
// ---------------------------------------------------------------------------
__global__ __launch_bounds__(256) void finalize_kernel(const float* __restrict__ st,
                                                       const float* __restrict__ pm,
                                                       const float* __restrict__ pl,
                                                       const float* __restrict__ pc,
                                                       float* __restrict__ out) {
  const int wv = threadIdx.x >> 6, lane = threadIdx.x & 63;
  const int qi = blockIdx.x * 4 + wv;
  float4 m4 = ((const float4*)(pm + (size_t)qi * NCHUNKS))[lane];
  float mx = fmaxf(fmaxf(m4.x, m4.y), fmaxf(m4.z, m4.w));
#pragma unroll
  for (int off = 32; off >= 1; off >>= 1) mx = fmaxf(mx, __shfl_xor(mx, off));
  float4 l4 = ((const float4*)(pl + (size_t)qi * NCHUNKS))[lane];
  float4 c4 = ((const float4*)(pc + (size_t)qi * NCHUNKS))[lane];
  float l = l4.x * __expf(m4.x - mx) + l4.y * __expf(m4.y - mx) +
            l4.z * __expf(m4.z - mx) + l4.w * __expf(m4.w - mx);
  float c = c4.x + c4.y + c4.z + c4.w;
#pragma unroll
  for (int off = 32; off >= 1; off >>= 1) {
    l += __shfl_xor(l, off);
    c += __shfl_xor(c, off);
  }
  float loss = 0.f;
  if (lane == 0) {
    const float raw = logf(l) + mx - st[qi];   // -log_softmax[target]
    const float dr = c - 1.0f;                 // rank - OPTIMAL_RANK
    const float w = 1.0f + ALPHA_C * __expf(-(dr * dr) * INV_2SIG2);
    loss = raw * w * (1.0f / (float)BQ);
  }
  __shared__ float red[4];
  if (lane == 0) red[wv] = loss;
  __syncthreads();
  if (threadIdx.x == 0) atomicAdd(out, red[0] + red[1] + red[2] + red[3]);
}

// ---------------------------------------------------------------------------
extern "C" void kernel_launch(void* const* d_in, const int* in_sizes, int n_in,
                              void* d_out, int out_size, void* d_ws, size_t ws_size,
                              hipStream_t stream) {
  const float* q = (const float*)d_in[0];
  const float* p = (const float*)d_in[1];
  char* ws = (char*)d_ws;
  unsigned char* qb = (unsigned char*)ws;                  // 1,572,864 B
  unsigned char* pb = (unsigned char*)(ws + 1572864);      // 12,582,912 B
  float* st = (float*)(ws + 14155776);                     // 8 KB
  float* pm = (float*)(ws + 14163968);                     // 2 MB
  float* pl = (float*)(ws + 16261120);                     // 2 MB
  float* pc = (float*)(ws + 18358272);                     // 2 MB (end ~20.5 MB)
  float* out = (float*)d_out;

  prep_kernel<<<NCB + BQ / 4, 256, 0, stream>>>(q, p, (uint2*)qb, (uint2*)pb, st, out);
  gemm_kernel<<<NBLK * MBLK, 512, 0, stream>>>(qb, pb, st, pm, pl, pc);
  finalize_kernel<<<BQ / 4, 256, 0, stream>>>(st, pm, pl, pc, out);
}

// Round 10
// 163.653 us; speedup vs baseline: 1.7382x; 1.7382x over previous
//
#include <hip/hip_runtime.h>
#include <math.h>

// Problem: scores = q[2048x768] @ p[16384x768]^T (fp32 in), per-query
// rank-of-target + log-softmax CE + Gaussian rank weight -> mean (scalar).
// R10 = R5 (best gemm, 75 us) with ONE change: XCD swizzle pins PB, not QB.
// R5's FETCH_SIZE=87MB == pb staged from HBM 8x (each XCD streamed all of
// pb through its 4MB L2 with zero reuse; qb fits every L2 anyway).
// New map: xcd=bid&7 owns pb slice nb in [xcd*8, xcd*8+8) (1.6 MB) + all
// qb (1.5 MB) = 3.1 MB < 4 MB L2 -> both operands L2-resident; staging at
// L2 BW (~1.2k cyc/phase) < MFMA (~5k cyc/phase) -> MFMA-bound phases.
// R8/R9 lesson: no-LDS + source-level pipelining regress (compiler waitcnt
// serializes VMEM latency); keep the R5 dbuf global_load_lds structure.

#define BQ 2048
#define DD 768
#define NPASS 8
#define PP 16384
#define BM 256
#define BN 256
#define BK 128
#define KITERS 6           // 768/128
#define NBLK 64            // PP/BN
#define MBLK 8             // BQ/BM
#define NCHUNKS 256        // NBLK * 4 n-waves

#define ALPHA_C 2.6f
#define INV_2SIG2 (1.0f/6.48f)   // 1/(2*1.8^2)

typedef __attribute__((ext_vector_type(4))) float floatx4;  // MFMA C/D

// ---------------------------------------------------------------------------
// Kernel 1 (fused): cast q,p -> fp8 e4m3  +  s_t exact-fp32 dots  +  out=0.
// ---------------------------------------------------------------------------
#define NQ8   196608     // 2048*768/8
#define NTOT8 1769472    // (2048+16384)*768/8
#define NCB   6912       // NTOT8/256
__global__ __launch_bounds__(256) void prep_kernel(const float* __restrict__ qf,
                                                   const float* __restrict__ pf,
                                                   uint2* __restrict__ qb,
                                                   uint2* __restrict__ pb,
                                                   float* __restrict__ st,
                                                   float* __restrict__ out) {
  const int b = blockIdx.x;
  if (b == 0 && threadIdx.x == 0) *out = 0.f;
  if (b < NCB) {
    const int i = b * 256 + threadIdx.x;        // float8 index
    const float4* src; uint2* dst;
    if (i < NQ8) { src = (const float4*)qf + 2 * (size_t)i; dst = qb + i; }
    else { const size_t j = (size_t)i - NQ8; src = (const float4*)pf + 2 * j; dst = pb + j; }
    const float4 a = src[0], c = src[1];
    unsigned lo = __builtin_amdgcn_cvt_pk_fp8_f32(a.x, a.y, 0, 0);
    lo = __builtin_amdgcn_cvt_pk_fp8_f32(a.z, a.w, lo, 1);
    unsigned hi = __builtin_amdgcn_cvt_pk_fp8_f32(c.x, c.y, 0, 0);
    hi = __builtin_amdgcn_cvt_pk_fp8_f32(c.z, c.w, hi, 1);
    uint2 w; w.x = lo; w.y = hi;
    *dst = w;
  } else {
    const int wv = threadIdx.x >> 6, lane = threadIdx.x & 63;
    const int qi = (b - NCB) * 4 + wv;
    const float4* q4 = (const float4*)(qf + (size_t)qi * DD);
    const float4* p4 = (const float4*)(pf + (size_t)qi * NPASS * DD);
    float acc = 0.f;
#pragma unroll
    for (int u = 0; u < 3; ++u) {   // 192 float4 per row = 64 lanes * 3
      float4 a = q4[lane + 64 * u];
      float4 c = p4[lane + 64 * u];
      acc = fmaf(a.x, c.x, acc);
      acc = fmaf(a.y, c.y, acc);
      acc = fmaf(a.z, c.z, acc);
      acc = fmaf(a.w, c.w, acc);
    }
#pragma unroll
    for (int off = 32; off >= 1; off >>= 1) acc += __shfl_xor(acc, off);
    if (lane == 0) st[qi] = acc;
  }
}

// ---------------------------------------------------------------------------
// Kernel 2: fp8 MFMA GEMM 256x256, BK=128, double-buffered staging (= R5).
// 16 waves (4x4), each wave 4x4 MFMAs of 16x16x32 fp8_fp8 (64x64 out).
// LDS unit = 16 rows x 64 k-bytes = 1 KB at (rowgrp*2+khalf)*1024; staged by
// one wave: lane (lm,lq) -> row lm, k-bytes lq*16 (wave-uniform base +
// lane*16 = global_load_lds semantics). Unit layout [kgrp(16B)][row][byte]:
// a-frag k = ks*32 + lq*8 + j -> intra = ((ks&1)*2+(lq>>1))*256+lm*16+(lq&1)*8
// (validated R4-R9, absmax 0.5). C/D: col=lane&15, row=(lane>>4)*4+reg.
// Grid swizzle (the R10 change): xcd=bid&7 owns pb slice nb in
// [xcd*8, xcd*8+8) -> pb fetched from HBM once ever; qb+pb slice L2-resident.
// ---------------------------------------------------------------------------
__global__ __launch_bounds__(1024) void gemm_kernel(const unsigned char* __restrict__ qb,
                                                    const unsigned char* __restrict__ pb,
                                                    const float* __restrict__ st,
                                                    float* __restrict__ pm,
                                                    float* __restrict__ pl,
                                                    float* __restrict__ pc) {
  __shared__ unsigned char As[2][32 * 1024];   // [buf][rowgrp*2+kh unit][1 KB]
  __shared__ unsigned char Bs[2][32 * 1024];
  __shared__ float st_lds[BM];

  const int t = threadIdx.x;
  const int lane = t & 63;
  const int wv = t >> 6;            // 0..15
  const int wm = wv >> 2, wn = wv & 3;
  const int bid = blockIdx.x;       // 0..511
  const int xcd = bid & 7;          // round-robin XCD assignment
  const int nb = xcd * 8 + ((bid >> 3) & 7);   // XCD-private pb slice (1.6 MB)
  const int mb = bid >> 6;          // 0..7
  const int qbase = mb * BM;
  const int n0 = nb * BN;
  const int lm = lane & 15;
  const int lq = lane >> 4;
  const int lds_lane = lane * 16;

  if (t < BM) st_lds[t] = st[qbase + t];

  floatx4 acc[4][4];
#pragma unroll
  for (int i = 0; i < 4; ++i)
#pragma unroll
    for (int j = 0; j < 4; ++j) acc[i][j] = (floatx4){0.f, 0.f, 0.f, 0.f};

  const size_t arow = (size_t)(qbase + wv * 16 + lm) * DD;
  const size_t brow = (size_t)(n0 + wv * 16 + lm) * DD;

  // stage(kt, buf): 4 loads/wave (A kh0/kh1, B kh0/kh1), 1 KB each
#define STAGE(KT, BUF)                                                          \
  {                                                                             \
    const size_t koff = (size_t)(KT) * BK + lq * 16;                            \
    _Pragma("unroll")                                                           \
    for (int kh = 0; kh < 2; ++kh) {                                            \
      __builtin_amdgcn_global_load_lds(                                         \
          (const __attribute__((address_space(1))) void*)(qb + arow + koff + kh * 64), \
          (__attribute__((address_space(3))) void*)(&As[BUF][(wv * 2 + kh) * 1024] + lds_lane), \
          16, 0, 0);                                                            \
      __builtin_amdgcn_global_load_lds(                                         \
          (const __attribute__((address_space(1))) void*)(pb + brow + koff + kh * 64), \
          (__attribute__((address_space(3))) void*)(&Bs[BUF][(wv * 2 + kh) * 1024] + lds_lane), \
          16, 0, 0);                                                            \
    }                                                                           \
  }

  STAGE(0, 0)
  for (int kt = 0; kt < KITERS; ++kt) {
    const int cb = kt & 1;
    __syncthreads();                 // drains vmcnt -> buf cb ready
    if (kt < KITERS - 1) STAGE(kt + 1, cb ^ 1)   // flies under compute below
#pragma unroll
    for (int ks = 0; ks < 4; ++ks) {
      const int kh = ks >> 1;
      const int intra = ((ks & 1) * 2 + (lq >> 1)) * 256 + lm * 16 + (lq & 1) * 8;
      long a[4], b[4];
#pragma unroll
      for (int i = 0; i < 4; ++i)
        a[i] = *(const long*)(&As[cb][((wm * 4 + i) * 2 + kh) * 1024] + intra);
#pragma unroll
      for (int j = 0; j < 4; ++j)
        b[j] = *(const long*)(&Bs[cb][((wn * 4 + j) * 2 + kh) * 1024] + intra);
#pragma unroll
      for (int i = 0; i < 4; ++i)
#pragma unroll
        for (int j = 0; j < 4; ++j)
          acc[i][j] = __builtin_amdgcn_mfma_f32_16x16x32_fp8_fp8(a[i], b[j], acc[i][j], 0, 0, 0);
    }
  }

  // ---- fused epilogue: per-row (query) max / sumexp / count over 64 cols ----
#pragma unroll
  for (int i = 0; i < 4; ++i) {
#pragma unroll
    for (int r = 0; r < 4; ++r) {
      const int rl = wm * 64 + i * 16 + lq * 4 + r;   // local query row
      float mx = fmaxf(fmaxf(acc[i][0][r], acc[i][1][r]),
                       fmaxf(acc[i][2][r], acc[i][3][r]));
#pragma unroll
      for (int off = 1; off <= 8; off <<= 1) mx = fmaxf(mx, __shfl_xor(mx, off));
      const float stv = st_lds[rl];
      const int qg = qbase + rl;
      const int tcol = qg * NPASS;
      float sum = 0.f, c = 0.f;
#pragma unroll
      for (int j = 0; j < 4; ++j) {
        const float s = acc[i][j][r];
        sum += __expf(s - mx);
        const int cg = n0 + wn * 64 + j * 16 + lm;
        if (s > stv && cg != tcol) c += 1.f;
      }
#pragma unroll
      for (int off = 1; off <= 8; off <<= 1) {
        sum += __shfl_xor(sum, off);
        c += __shfl_xor(c, off);
      }
      if (lm == 0) {
        const int chunk = nb * 4 + wn;
        const size_t idx = (size_t)qg * NCHUNKS + chunk;
        pm[idx] = mx; pl[idx] = sum; pc[idx] = c;
      }
    }
  }
}

// ---------------------------------------------------------------------------
// Kernel 3: merge 256 chunks/query, weighted CE, mean -> atomicAdd. 1 wave/query.
// ---------------------------------------------------------------------------
__global__ __launch_bounds__(256) void finalize_kernel(const float* __restrict__ st,
                                                       const float* __restrict__ pm,
                                                       const float* __restrict__ pl,
                                                       const float* __restrict__ pc,
                                                       float* __restrict__ out) {
  const int wv = threadIdx.x >> 6, lane = threadIdx.x & 63;
  const int qi = blockIdx.x * 4 + wv;
  float4 m4 = ((const float4*)(pm + (size_t)qi * NCHUNKS))[lane];
  float mx = fmaxf(fmaxf(m4.x, m4.y), fmaxf(m4.z, m4.w));
#pragma unroll
  for (int off = 32; off >= 1; off >>= 1) mx = fmaxf(mx, __shfl_xor(mx, off));
  float4 l4 = ((const float4*)(pl + (size_t)qi * NCHUNKS))[lane];
  float4 c4 = ((const float4*)(pc + (size_t)qi * NCHUNKS))[lane];
  float l = l4.x * __expf(m4.x - mx) + l4.y * __expf(m4.y - mx) +
            l4.z * __expf(m4.z - mx) + l4.w * __expf(m4.w - mx);
  float c = c4.x + c4.y + c4.z + c4.w;
#pragma unroll
  for (int off = 32; off >= 1; off >>= 1) {
    l += __shfl_xor(l, off);
    c += __shfl_xor(c, off);
  }
  float loss = 0.f;
  if (lane == 0) {
    const float raw = logf(l) + mx - st[qi];   // -log_softmax[target]
    const float dr = c - 1.0f;                 // rank - OPTIMAL_RANK
    const float w = 1.0f + ALPHA_C * __expf(-(dr * dr) * INV_2SIG2);
    loss = raw * w * (1.0f / (float)BQ);
  }
  __shared__ float red[4];
  if (lane == 0) red[wv] = loss;
  __syncthreads();
  if (threadIdx.x == 0) atomicAdd(out, red[0] + red[1] + red[2] + red[3]);
}

// ---------------------------------------------------------------------------
extern "C" void kernel_launch(void* const* d_in, const int* in_sizes, int n_in,
                              void* d_out, int out_size, void* d_ws, size_t ws_size,
                              hipStream_t stream) {
  const float* q = (const float*)d_in[0];
  const float* p = (const float*)d_in[1];
  char* ws = (char*)d_ws;
  unsigned char* qb = (unsigned char*)ws;                  // 1,572,864 B
  unsigned char* pb = (unsigned char*)(ws + 1572864);      // 12,582,912 B
  float* st = (float*)(ws + 14155776);                     // 8 KB
  float* pm = (float*)(ws + 14163968);                     // 2 MB
  float* pl = (float*)(ws + 16261120);                     // 2 MB
  float* pc = (float*)(ws + 18358272);                     // 2 MB (end ~20.5 MB)
  float* out = (float*)d_out;

  prep_kernel<<<NCB + BQ / 4, 256, 0, stream>>>(q, p, (uint2*)qb, (uint2*)pb, st, out);
  gemm_kernel<<<NBLK * MBLK, 1024, 0, stream>>>(qb, pb, st, pm, pl, pc);
  finalize_kernel<<<BQ / 4, 256, 0, stream>>>(st, pm, pl, pc, out);
}